// Round 5
// baseline (177.052 us; speedup 1.0000x reference)
//
#include <hip/hip_runtime.h>

typedef unsigned short u16;
typedef unsigned int   u32;
typedef __attribute__((ext_vector_type(8))) short bf16x8;
typedef __attribute__((ext_vector_type(4))) float f32x4;

#define LROW 4096
#define NB   8192
#define PCOL 720
#define NPAD 768
#define HH   2048
#define INV_SQRT2F 0.70710678118654752440f

// ws layout: xbf | G | std
#define WS_XBF_BYTES ((size_t)67108864)           // 8192*4096*2
#define WS_G_BYTES   ((size_t)6291456)            // 768*4096*2
#define WS_MIN       (WS_XBF_BYTES + WS_G_BYTES + (size_t)NB * 4)

__device__ __forceinline__ u16 f2bf(float f) {
    union { float f; u32 u; } v; v.f = f;
    u32 r = v.u + 0x7FFFu + ((v.u >> 16) & 1u);
    return (u16)(r >> 16);
}

#define SWZ(i) ((i) ^ (((i) >> 5) & 31))

// ---------------------------------------------------------------------------
// Kernel P: per-row moving-average (via prefix sum), std (ddof=1), x -> bf16
// ---------------------------------------------------------------------------
__global__ __launch_bounds__(256) void prep_rows(const float* __restrict__ x,
                                                 u16* __restrict__ xbf,
                                                 float* __restrict__ stdv) {
    __shared__ float S[LROW];
    __shared__ float wred[4];
    __shared__ float ends[2];
    __shared__ float rred[8];
    const int tid = threadIdx.x;
    const int lane = tid & 63, wv = tid >> 6;
    const size_t b = blockIdx.x;

    const float4* xr4 = (const float4*)(x + b * LROW);
    float4 q0 = xr4[tid * 4 + 0], q1 = xr4[tid * 4 + 1];
    float4 q2 = xr4[tid * 4 + 2], q3 = xr4[tid * 4 + 3];
    float r[16];
    r[0]=q0.x; r[1]=q0.y; r[2]=q0.z; r[3]=q0.w;
    r[4]=q1.x; r[5]=q1.y; r[6]=q1.z; r[7]=q1.w;
    r[8]=q2.x; r[9]=q2.y; r[10]=q2.z; r[11]=q2.w;
    r[12]=q3.x; r[13]=q3.y; r[14]=q3.z; r[15]=q3.w;

    float ps[16];
    float a = 0.f;
    #pragma unroll
    for (int k = 0; k < 16; ++k) { a += r[k]; ps[k] = a; }
    const float segsum = a;

    float v = segsum;
    #pragma unroll
    for (int off = 1; off < 64; off <<= 1) {
        float o = __shfl_up(v, off);
        if (lane >= off) v += o;
    }
    if (lane == 63) wred[wv] = v;
    if (tid == 0)   ends[0] = r[0];
    if (tid == 255) ends[1] = r[15];
    __syncthreads();

    float wbase = 0.f;
    #pragma unroll
    for (int w = 0; w < 4; ++w) if (w < wv) wbase += wred[w];
    const float ebase = wbase + v - segsum;

    #pragma unroll
    for (int k = 0; k < 16; ++k) {
        const int i = (tid << 4) + k;
        S[SWZ(i)] = ebase + ps[k];
    }
    __syncthreads();

    const float x0 = ends[0], xl = ends[1];
    float s1 = 0.f, s2 = 0.f;
    u16 ob[16];
    #pragma unroll
    for (int k = 0; k < 16; ++k) {
        const int i = (tid << 4) + k;
        int h = i + 12; h = h > LROW - 1 ? LROW - 1 : h;
        float wsum = S[SWZ(h)];
        if (i >= 13) wsum -= S[SWZ(i - 13)];
        if (i < 12) wsum += (float)(12 - i) * x0;
        if (i > LROW - 13) wsum += (float)(i - (LROW - 13)) * xl;
        const float xi = r[k];
        const float rr = xi - wsum * 0.04f;
        s1 += rr; s2 += rr * rr;
        ob[k] = f2bf(xi);
    }

    uint4 o0, o1;
    o0.x = (u32)ob[0]  | ((u32)ob[1]  << 16);
    o0.y = (u32)ob[2]  | ((u32)ob[3]  << 16);
    o0.z = (u32)ob[4]  | ((u32)ob[5]  << 16);
    o0.w = (u32)ob[6]  | ((u32)ob[7]  << 16);
    o1.x = (u32)ob[8]  | ((u32)ob[9]  << 16);
    o1.y = (u32)ob[10] | ((u32)ob[11] << 16);
    o1.z = (u32)ob[12] | ((u32)ob[13] << 16);
    o1.w = (u32)ob[14] | ((u32)ob[15] << 16);
    uint4* op = (uint4*)(xbf + b * LROW + ((size_t)tid << 4));
    op[0] = o0; op[1] = o1;

    #pragma unroll
    for (int off = 32; off; off >>= 1) {
        s1 += __shfl_down(s1, off);
        s2 += __shfl_down(s2, off);
    }
    if (lane == 0) { rred[wv * 2] = s1; rred[wv * 2 + 1] = s2; }
    __syncthreads();
    if (tid == 0) {
        const float S1 = rred[0] + rred[2] + rred[4] + rred[6];
        const float S2 = rred[1] + rred[3] + rred[5] + rred[7];
        const float mean = S1 / (float)LROW;
        float var = (S2 - (float)LROW * mean * mean) / (float)(LROW - 1);
        var = var < 0.f ? 0.f : var;
        stdv[b] = sqrtf(var) + 1e-5f;
    }
}

// ---------------------------------------------------------------------------
// Kernel W: fold weights into G[p][l] (bf16), rows 720..767 zero-padded.
// ---------------------------------------------------------------------------
__global__ __launch_bounds__(256) void prep_weights(const float* __restrict__ Wt,
                                                    const float* __restrict__ Wlo,
                                                    const float* __restrict__ Whi,
                                                    u16* __restrict__ Gm) {
    __shared__ float S[LROW];
    __shared__ float wred[4];
    __shared__ float sred[4];
    const int tid = threadIdx.x;
    const int lane = tid & 63, wv = tid >> 6;
    const int p = blockIdx.x;
    u16* grow = Gm + (size_t)p * LROW;
    if (p >= PCOL) {
        uint4 z; z.x = z.y = z.z = z.w = 0u;
        uint4* g4 = (uint4*)grow;
        for (int i = tid; i < LROW / 8; i += 256) g4[i] = z;
        return;
    }
    const float4* wt4 = (const float4*)(Wt + (size_t)p * LROW);
    float4 q0 = wt4[tid * 4 + 0], q1 = wt4[tid * 4 + 1];
    float4 q2 = wt4[tid * 4 + 2], q3 = wt4[tid * 4 + 3];
    const float4* lo4 = (const float4*)(Wlo + (size_t)p * HH);
    const float4* hi4 = (const float4*)(Whi + (size_t)p * HH);
    float4 a0 = lo4[tid * 2 + 0], a1 = lo4[tid * 2 + 1];
    float4 b0 = hi4[tid * 2 + 0], b1 = hi4[tid * 2 + 1];

    float w[16];
    w[0]=q0.x; w[1]=q0.y; w[2]=q0.z; w[3]=q0.w;
    w[4]=q1.x; w[5]=q1.y; w[6]=q1.z; w[7]=q1.w;
    w[8]=q2.x; w[9]=q2.y; w[10]=q2.z; w[11]=q2.w;
    w[12]=q3.x; w[13]=q3.y; w[14]=q3.z; w[15]=q3.w;
    float lv[8] = {a0.x,a0.y,a0.z,a0.w,a1.x,a1.y,a1.z,a1.w};
    float hv[8] = {b0.x,b0.y,b0.z,b0.w,b1.x,b1.y,b1.z,b1.w};

    float u[16], z_[16];
    float slo = 0.f;
    #pragma unroll
    for (int j = 0; j < 8; ++j) {
        u[2*j]   = (lv[j] + hv[j]) * INV_SQRT2F;
        u[2*j+1] = (lv[j] - hv[j]) * INV_SQRT2F;
        slo += lv[j];
    }
    #pragma unroll
    for (int k = 0; k < 16; ++k) z_[k] = w[k] - u[k];

    float ps[16];
    float a = 0.f;
    #pragma unroll
    for (int k = 0; k < 16; ++k) { a += z_[k]; ps[k] = a; }
    const float segsum = a;

    float v = segsum;
    #pragma unroll
    for (int off = 1; off < 64; off <<= 1) {
        float o = __shfl_up(v, off);
        if (lane >= off) v += o;
    }
    if (lane == 63) wred[wv] = v;
    #pragma unroll
    for (int off = 32; off; off >>= 1) slo += __shfl_down(slo, off);
    if (lane == 0) sred[wv] = slo;
    __syncthreads();

    float wbase = 0.f;
    #pragma unroll
    for (int ww = 0; ww < 4; ++ww) if (ww < wv) wbase += wred[ww];
    const float ebase = wbase + v - segsum;
    const float SLO = sred[0] + sred[1] + sred[2] + sred[3];

    #pragma unroll
    for (int k = 0; k < 16; ++k) {
        const int i = (tid << 4) + k;
        S[SWZ(i)] = ebase + ps[k];
    }
    __syncthreads();

    const float coef = -1.4142135623730951f * SLO / (float)LROW;
    u16 ob[16];
    #pragma unroll
    for (int k = 0; k < 16; ++k) {
        const int l = (tid << 4) + k;
        float zT;
        if (l == 0) {
            float acc = 0.f;
            for (int m = 0; m <= 12; ++m) acc += S[SWZ(m)];
            zT = acc * 0.04f;
        } else if (l == LROW - 1) {
            float acc = 0.f;
            for (int m = 0; m <= 12; ++m) acc += S[SWZ(LROW - 2 - m)];
            zT = (13.f * S[SWZ(LROW - 1)] - acc) * 0.04f;
        } else {
            int h = l + 12; h = h > LROW - 1 ? LROW - 1 : h;
            float t_ = S[SWZ(h)];
            if (l >= 13) t_ -= S[SWZ(l - 13)];
            zT = t_ * 0.04f;
        }
        float c;
        const int dmin = l < (LROW - 1 - l) ? l : (LROW - 1 - l);
        if (dmin >= 12)      c = 0.f;
        else if (dmin == 0)  c = -66.f / 25.f;
        else                 c = (float)(12 - dmin) * 0.04f;
        ob[k] = f2bf(zT + u[k] + coef * c);
    }

    uint4 o0, o1;
    o0.x = (u32)ob[0]  | ((u32)ob[1]  << 16);
    o0.y = (u32)ob[2]  | ((u32)ob[3]  << 16);
    o0.z = (u32)ob[4]  | ((u32)ob[5]  << 16);
    o0.w = (u32)ob[6]  | ((u32)ob[7]  << 16);
    o1.x = (u32)ob[8]  | ((u32)ob[9]  << 16);
    o1.y = (u32)ob[10] | ((u32)ob[11] << 16);
    o1.z = (u32)ob[12] | ((u32)ob[13] << 16);
    o1.w = (u32)ob[14] | ((u32)ob[15] << 16);
    uint4* op = (uint4*)(grow + ((size_t)tid << 4));
    op[0] = o0; op[1] = o1;
}

// ---------------------------------------------------------------------------
// Kernel G: fused GEMM, BM=128 BN=96 BK=64, 4 waves (2m x 2n), 64 iters.
// A: global->reg direct, frag sets double-buffered (lead-1; A is L3-resident).
// B: LDS 3-deep (12KB/buf), staged lead-2 via global_load_lds, XOR-swizzled
// (pre-swizzled source, rule #21). One barrier/iter; top wait = vmcnt(8)
// (retires exactly last iter's 3 B-stage loads) + lgkm(0) no-op. MFMAs use
// registers loaded last iter -> no load latency on critical path. Bias fused.
// ---------------------------------------------------------------------------
typedef __attribute__((address_space(1))) void gvoid;
typedef __attribute__((address_space(3))) void lvoid;
#define GLD16(g, l_) __builtin_amdgcn_global_load_lds((gvoid*)(g), (lvoid*)(l_), 16, 0, 0)
#define MF(a, b, c) __builtin_amdgcn_mfma_f32_16x16x32_bf16(a, b, c, 0, 0, 0)

#define BBUF 12288            // 96 rows x 128 B per buffer

#define STAGE_B(T, STOFF) do { \
    const size_t go_ = (size_t)(T) * 128; \
    GLD16(gb0 + go_, Sm + (STOFF) + lb0); \
    GLD16(gb1 + go_, Sm + (STOFF) + lb1); \
    GLD16(gb2 + go_, Sm + (STOFF) + lb2); \
} while (0)

#define LOAD_A(T, S) do { \
    const char* s_ = pa + (size_t)(T) * 128; \
    S[0][0] = *(const bf16x8*)(s_); \
    S[0][1] = *(const bf16x8*)(s_ + 131072); \
    S[0][2] = *(const bf16x8*)(s_ + 262144); \
    S[0][3] = *(const bf16x8*)(s_ + 393216); \
    S[1][0] = *(const bf16x8*)(s_ + 64); \
    S[1][1] = *(const bf16x8*)(s_ + 131072 + 64); \
    S[1][2] = *(const bf16x8*)(s_ + 262144 + 64); \
    S[1][3] = *(const bf16x8*)(s_ + 393216 + 64); \
} while (0)

#define ITER(T, AC, AL, RDOFF, STOFF, DOSTAGE, DOLOADA) do { \
    asm volatile("s_waitcnt vmcnt(8) lgkmcnt(0)" ::: "memory"); \
    __builtin_amdgcn_s_barrier(); \
    __builtin_amdgcn_sched_barrier(0); \
    if (DOSTAGE) { STAGE_B((T) + 2, STOFF); } \
    __builtin_amdgcn_sched_barrier(0); \
    if (DOLOADA) { LOAD_A((T) + 1, AL); } \
    const char* r_ = (const char*)Sm + (RDOFF); \
    bf16x8 b00 = *(const bf16x8*)(r_ + lofs0); \
    bf16x8 b01 = *(const bf16x8*)(r_ + lofs0 + 2048); \
    bf16x8 b02 = *(const bf16x8*)(r_ + lofs0 + 4096); \
    bf16x8 b10 = *(const bf16x8*)(r_ + lofs1); \
    bf16x8 b11 = *(const bf16x8*)(r_ + lofs1 + 2048); \
    bf16x8 b12 = *(const bf16x8*)(r_ + lofs1 + 4096); \
    __builtin_amdgcn_s_setprio(1); \
    acc[0][0] = MF(AC[0][0], b00, acc[0][0]); \
    acc[0][1] = MF(AC[0][0], b01, acc[0][1]); \
    acc[0][2] = MF(AC[0][0], b02, acc[0][2]); \
    acc[1][0] = MF(AC[0][1], b00, acc[1][0]); \
    acc[1][1] = MF(AC[0][1], b01, acc[1][1]); \
    acc[1][2] = MF(AC[0][1], b02, acc[1][2]); \
    acc[2][0] = MF(AC[0][2], b00, acc[2][0]); \
    acc[2][1] = MF(AC[0][2], b01, acc[2][1]); \
    acc[2][2] = MF(AC[0][2], b02, acc[2][2]); \
    acc[3][0] = MF(AC[0][3], b00, acc[3][0]); \
    acc[3][1] = MF(AC[0][3], b01, acc[3][1]); \
    acc[3][2] = MF(AC[0][3], b02, acc[3][2]); \
    acc[0][0] = MF(AC[1][0], b10, acc[0][0]); \
    acc[0][1] = MF(AC[1][0], b11, acc[0][1]); \
    acc[0][2] = MF(AC[1][0], b12, acc[0][2]); \
    acc[1][0] = MF(AC[1][1], b10, acc[1][0]); \
    acc[1][1] = MF(AC[1][1], b11, acc[1][1]); \
    acc[1][2] = MF(AC[1][1], b12, acc[1][2]); \
    acc[2][0] = MF(AC[1][2], b10, acc[2][0]); \
    acc[2][1] = MF(AC[1][2], b11, acc[2][1]); \
    acc[2][2] = MF(AC[1][2], b12, acc[2][2]); \
    acc[3][0] = MF(AC[1][3], b10, acc[3][0]); \
    acc[3][1] = MF(AC[1][3], b11, acc[3][1]); \
    acc[3][2] = MF(AC[1][3], b12, acc[3][2]); \
    __builtin_amdgcn_s_setprio(0); \
} while (0)

__global__ __launch_bounds__(256, 2) void gemm_fused(const u16* __restrict__ Abf,
                                                     const u16* __restrict__ Gbf,
                                                     const float* __restrict__ bt,
                                                     const float* __restrict__ bl,
                                                     const float* __restrict__ bh,
                                                     const float* __restrict__ stdv,
                                                     float* __restrict__ out) {
    __shared__ __align__(16) char Sm[3 * BBUF];   // 36864 B
    const int tid = threadIdx.x;
    const int l = tid & 63, wid = tid >> 6;
    const int wm = wid >> 1, wn = wid & 1;

    // XCD-chunked swizzle: 512 = 8 XCDs x 64; n fastest within chunk
    const int orig = blockIdx.x;
    const int chunk = orig & 7, pos = orig >> 3;
    const int bx = pos & 7;
    const int by = (chunk << 3) + (pos >> 3);
    const int m0 = by * 128;
    const int n0 = bx * 96;

    // ---- A: per-lane global->reg pointers. lane: row (l&15)+16m, slot l>>4 ----
    const char* pa = (const char*)Abf
        + ((size_t)(m0 + wm * 64 + (l & 15)) << 13) + ((l >> 4) << 4);

    // ---- B staging: 12 instrs of 1024B (8 rows each); wave handles 3 ----
    // LDS(row, s) = G(row, s ^ (row&7)); lane l in instr: row +(l>>3), slot l&7
    const int sgb = (((l & 7) ^ (l >> 3)) << 4);
    const char* gb0 = (const char*)Gbf + ((size_t)(n0 + wid * 24 +  0 + (l >> 3)) << 13) + sgb;
    const char* gb1 = (const char*)Gbf + ((size_t)(n0 + wid * 24 +  8 + (l >> 3)) << 13) + sgb;
    const char* gb2 = (const char*)Gbf + ((size_t)(n0 + wid * 24 + 16 + (l >> 3)) << 13) + sgb;
    const int lb0 = (wid * 3 + 0) * 1024;
    const int lb1 = (wid * 3 + 1) * 1024;
    const int lb2 = (wid * 3 + 2) * 1024;

    // ---- B frag read offsets (swizzled): row = wn*48+n*16+(l&15), row&7 = l&7
    const int lofs0 = (wn * 48 + (l & 15)) * 128 + ((((l >> 4)    ) ^ (l & 7)) << 4);
    const int lofs1 = (wn * 48 + (l & 15)) * 128 + ((((l >> 4) + 4) ^ (l & 7)) << 4);

    f32x4 acc[4][3] = {};
    bf16x8 A0F[2][4], A1F[2][4];

    // prologue: B tiles 0,1 staged; A tile 0 in regs
    STAGE_B(0, 0);
    STAGE_B(1, BBUF);
    __builtin_amdgcn_sched_barrier(0);
    LOAD_A(0, A0F);

    for (int t = 0; t < 60; t += 6) {
        ITER(t + 0, A0F, A1F, 0,        2 * BBUF, 1, 1);
        ITER(t + 1, A1F, A0F, BBUF,     0,        1, 1);
        ITER(t + 2, A0F, A1F, 2 * BBUF, BBUF,     1, 1);
        ITER(t + 3, A1F, A0F, 0,        2 * BBUF, 1, 1);
        ITER(t + 4, A0F, A1F, BBUF,     0,        1, 1);
        ITER(t + 5, A1F, A0F, 2 * BBUF, BBUF,     1, 1);
    }
    ITER(60, A0F, A1F, 0,        2 * BBUF, 1, 1);
    ITER(61, A1F, A0F, BBUF,     0,        1, 1);
    ITER(62, A0F, A1F, 2 * BBUF, 0,        0, 1);
    ITER(63, A1F, A0F, 0,        0,        0, 0);

    // ---- epilogue: out = acc + bt + std*(bl+bh) ----
    const int crow = m0 + wm * 64 + ((l >> 4) << 2);
    const int ccol = n0 + wn * 48 + (l & 15);
    float btv[3], bsv[3];
    #pragma unroll
    for (int n = 0; n < 3; ++n) {
        const int col = ccol + n * 16;
        if (col < PCOL) { btv[n] = bt[col]; bsv[n] = bl[col] + bh[col]; }
        else            { btv[n] = 0.f; bsv[n] = 0.f; }
    }
    #pragma unroll
    for (int m = 0; m < 4; ++m) {
        const int row = crow + m * 16;
        const float4 sv = *(const float4*)(stdv + row);
        #pragma unroll
        for (int n = 0; n < 3; ++n) {
            const int col = ccol + n * 16;
            if (col < PCOL) {
                float* orow = out + (size_t)row * PCOL + col;
                #pragma unroll
                for (int j = 0; j < 4; ++j) {
                    const float s = (j == 0) ? sv.x : (j == 1) ? sv.y : (j == 2) ? sv.z : sv.w;
                    orow[(size_t)j * PCOL] = acc[m][n][j] + btv[n] + s * bsv[n];
                }
            }
        }
    }
}

// ---------------------------------------------------------------------------
extern "C" void kernel_launch(void* const* d_in, const int* in_sizes, int n_in,
                              void* d_out, int out_size, void* d_ws, size_t ws_size,
                              hipStream_t stream) {
    (void)in_sizes; (void)n_in; (void)out_size;
    if (ws_size < WS_MIN) return;

    const float* x  = (const float*)d_in[0];
    const float* Wt = (const float*)d_in[1];
    const float* bt = (const float*)d_in[2];
    const float* Wl = (const float*)d_in[3];
    const float* bl = (const float*)d_in[4];
    const float* Wh = (const float*)d_in[5];
    const float* bh = (const float*)d_in[6];
    float* out = (float*)d_out;

    char* ws = (char*)d_ws;
    u16*   xbf = (u16*)ws;
    u16*   Gm  = (u16*)(ws + WS_XBF_BYTES);
    float* sd  = (float*)(ws + WS_XBF_BYTES + WS_G_BYTES);

    prep_rows<<<NB, 256, 0, stream>>>(x, xbf, sd);
    prep_weights<<<NPAD, 256, 0, stream>>>(Wt, Wl, Wh, Gm);
    gemm_fused<<<512, 256, 0, stream>>>(xbf, Gm, bt, bl, bh, sd, out);
}

// Round 6
// 100.232 us; speedup vs baseline: 1.7664x; 1.7664x over previous
//
#include <hip/hip_runtime.h>

typedef unsigned short u16;
typedef unsigned int   u32;
typedef __attribute__((ext_vector_type(8))) short bf16x8;
typedef __attribute__((ext_vector_type(4))) float f32x4;

#define LROW 4096
#define NB   8192
#define PCOL 720
#define NPAD 768
#define HH   2048
#define INV_SQRT2F 0.70710678118654752440f

// ws layout: xbf | G | std
#define WS_XBF_BYTES ((size_t)67108864)           // 8192*4096*2
#define WS_G_BYTES   ((size_t)6291456)            // 768*4096*2
#define WS_MIN       (WS_XBF_BYTES + WS_G_BYTES + (size_t)NB * 4)

__device__ __forceinline__ u16 f2bf(float f) {
    union { float f; u32 u; } v; v.f = f;
    u32 r = v.u + 0x7FFFu + ((v.u >> 16) & 1u);
    return (u16)(r >> 16);
}

#define SWZ(i) ((i) ^ (((i) >> 5) & 31))

// ---------------------------------------------------------------------------
// Kernel P: per-row moving-average (via prefix sum), std (ddof=1), x -> bf16
// ---------------------------------------------------------------------------
__global__ __launch_bounds__(256) void prep_rows(const float* __restrict__ x,
                                                 u16* __restrict__ xbf,
                                                 float* __restrict__ stdv) {
    __shared__ float S[LROW];
    __shared__ float wred[4];
    __shared__ float ends[2];
    __shared__ float rred[8];
    const int tid = threadIdx.x;
    const int lane = tid & 63, wv = tid >> 6;
    const size_t b = blockIdx.x;

    const float4* xr4 = (const float4*)(x + b * LROW);
    float4 q0 = xr4[tid * 4 + 0], q1 = xr4[tid * 4 + 1];
    float4 q2 = xr4[tid * 4 + 2], q3 = xr4[tid * 4 + 3];
    float r[16];
    r[0]=q0.x; r[1]=q0.y; r[2]=q0.z; r[3]=q0.w;
    r[4]=q1.x; r[5]=q1.y; r[6]=q1.z; r[7]=q1.w;
    r[8]=q2.x; r[9]=q2.y; r[10]=q2.z; r[11]=q2.w;
    r[12]=q3.x; r[13]=q3.y; r[14]=q3.z; r[15]=q3.w;

    float ps[16];
    float a = 0.f;
    #pragma unroll
    for (int k = 0; k < 16; ++k) { a += r[k]; ps[k] = a; }
    const float segsum = a;

    float v = segsum;
    #pragma unroll
    for (int off = 1; off < 64; off <<= 1) {
        float o = __shfl_up(v, off);
        if (lane >= off) v += o;
    }
    if (lane == 63) wred[wv] = v;
    if (tid == 0)   ends[0] = r[0];
    if (tid == 255) ends[1] = r[15];
    __syncthreads();

    float wbase = 0.f;
    #pragma unroll
    for (int w = 0; w < 4; ++w) if (w < wv) wbase += wred[w];
    const float ebase = wbase + v - segsum;

    #pragma unroll
    for (int k = 0; k < 16; ++k) {
        const int i = (tid << 4) + k;
        S[SWZ(i)] = ebase + ps[k];
    }
    __syncthreads();

    const float x0 = ends[0], xl = ends[1];
    float s1 = 0.f, s2 = 0.f;
    u16 ob[16];
    #pragma unroll
    for (int k = 0; k < 16; ++k) {
        const int i = (tid << 4) + k;
        int h = i + 12; h = h > LROW - 1 ? LROW - 1 : h;
        float wsum = S[SWZ(h)];
        if (i >= 13) wsum -= S[SWZ(i - 13)];
        if (i < 12) wsum += (float)(12 - i) * x0;
        if (i > LROW - 13) wsum += (float)(i - (LROW - 13)) * xl;
        const float xi = r[k];
        const float rr = xi - wsum * 0.04f;
        s1 += rr; s2 += rr * rr;
        ob[k] = f2bf(xi);
    }

    uint4 o0, o1;
    o0.x = (u32)ob[0]  | ((u32)ob[1]  << 16);
    o0.y = (u32)ob[2]  | ((u32)ob[3]  << 16);
    o0.z = (u32)ob[4]  | ((u32)ob[5]  << 16);
    o0.w = (u32)ob[6]  | ((u32)ob[7]  << 16);
    o1.x = (u32)ob[8]  | ((u32)ob[9]  << 16);
    o1.y = (u32)ob[10] | ((u32)ob[11] << 16);
    o1.z = (u32)ob[12] | ((u32)ob[13] << 16);
    o1.w = (u32)ob[14] | ((u32)ob[15] << 16);
    uint4* op = (uint4*)(xbf + b * LROW + ((size_t)tid << 4));
    op[0] = o0; op[1] = o1;

    #pragma unroll
    for (int off = 32; off; off >>= 1) {
        s1 += __shfl_down(s1, off);
        s2 += __shfl_down(s2, off);
    }
    if (lane == 0) { rred[wv * 2] = s1; rred[wv * 2 + 1] = s2; }
    __syncthreads();
    if (tid == 0) {
        const float S1 = rred[0] + rred[2] + rred[4] + rred[6];
        const float S2 = rred[1] + rred[3] + rred[5] + rred[7];
        const float mean = S1 / (float)LROW;
        float var = (S2 - (float)LROW * mean * mean) / (float)(LROW - 1);
        var = var < 0.f ? 0.f : var;
        stdv[b] = sqrtf(var) + 1e-5f;
    }
}

// ---------------------------------------------------------------------------
// Kernel W: fold weights into G[p][l] (bf16), rows 720..767 zero-padded.
// ---------------------------------------------------------------------------
__global__ __launch_bounds__(256) void prep_weights(const float* __restrict__ Wt,
                                                    const float* __restrict__ Wlo,
                                                    const float* __restrict__ Whi,
                                                    u16* __restrict__ Gm) {
    __shared__ float S[LROW];
    __shared__ float wred[4];
    __shared__ float sred[4];
    const int tid = threadIdx.x;
    const int lane = tid & 63, wv = tid >> 6;
    const int p = blockIdx.x;
    u16* grow = Gm + (size_t)p * LROW;
    if (p >= PCOL) {
        uint4 z; z.x = z.y = z.z = z.w = 0u;
        uint4* g4 = (uint4*)grow;
        for (int i = tid; i < LROW / 8; i += 256) g4[i] = z;
        return;
    }
    const float4* wt4 = (const float4*)(Wt + (size_t)p * LROW);
    float4 q0 = wt4[tid * 4 + 0], q1 = wt4[tid * 4 + 1];
    float4 q2 = wt4[tid * 4 + 2], q3 = wt4[tid * 4 + 3];
    const float4* lo4 = (const float4*)(Wlo + (size_t)p * HH);
    const float4* hi4 = (const float4*)(Whi + (size_t)p * HH);
    float4 a0 = lo4[tid * 2 + 0], a1 = lo4[tid * 2 + 1];
    float4 b0 = hi4[tid * 2 + 0], b1 = hi4[tid * 2 + 1];

    float w[16];
    w[0]=q0.x; w[1]=q0.y; w[2]=q0.z; w[3]=q0.w;
    w[4]=q1.x; w[5]=q1.y; w[6]=q1.z; w[7]=q1.w;
    w[8]=q2.x; w[9]=q2.y; w[10]=q2.z; w[11]=q2.w;
    w[12]=q3.x; w[13]=q3.y; w[14]=q3.z; w[15]=q3.w;
    float lv[8] = {a0.x,a0.y,a0.z,a0.w,a1.x,a1.y,a1.z,a1.w};
    float hv[8] = {b0.x,b0.y,b0.z,b0.w,b1.x,b1.y,b1.z,b1.w};

    float u[16], z_[16];
    float slo = 0.f;
    #pragma unroll
    for (int j = 0; j < 8; ++j) {
        u[2*j]   = (lv[j] + hv[j]) * INV_SQRT2F;
        u[2*j+1] = (lv[j] - hv[j]) * INV_SQRT2F;
        slo += lv[j];
    }
    #pragma unroll
    for (int k = 0; k < 16; ++k) z_[k] = w[k] - u[k];

    float ps[16];
    float a = 0.f;
    #pragma unroll
    for (int k = 0; k < 16; ++k) { a += z_[k]; ps[k] = a; }
    const float segsum = a;

    float v = segsum;
    #pragma unroll
    for (int off = 1; off < 64; off <<= 1) {
        float o = __shfl_up(v, off);
        if (lane >= off) v += o;
    }
    if (lane == 63) wred[wv] = v;
    #pragma unroll
    for (int off = 32; off; off >>= 1) slo += __shfl_down(slo, off);
    if (lane == 0) sred[wv] = slo;
    __syncthreads();

    float wbase = 0.f;
    #pragma unroll
    for (int ww = 0; ww < 4; ++ww) if (ww < wv) wbase += wred[ww];
    const float ebase = wbase + v - segsum;
    const float SLO = sred[0] + sred[1] + sred[2] + sred[3];

    #pragma unroll
    for (int k = 0; k < 16; ++k) {
        const int i = (tid << 4) + k;
        S[SWZ(i)] = ebase + ps[k];
    }
    __syncthreads();

    const float coef = -1.4142135623730951f * SLO / (float)LROW;
    u16 ob[16];
    #pragma unroll
    for (int k = 0; k < 16; ++k) {
        const int l = (tid << 4) + k;
        float zT;
        if (l == 0) {
            float acc = 0.f;
            for (int m = 0; m <= 12; ++m) acc += S[SWZ(m)];
            zT = acc * 0.04f;
        } else if (l == LROW - 1) {
            float acc = 0.f;
            for (int m = 0; m <= 12; ++m) acc += S[SWZ(LROW - 2 - m)];
            zT = (13.f * S[SWZ(LROW - 1)] - acc) * 0.04f;
        } else {
            int h = l + 12; h = h > LROW - 1 ? LROW - 1 : h;
            float t_ = S[SWZ(h)];
            if (l >= 13) t_ -= S[SWZ(l - 13)];
            zT = t_ * 0.04f;
        }
        float c;
        const int dmin = l < (LROW - 1 - l) ? l : (LROW - 1 - l);
        if (dmin >= 12)      c = 0.f;
        else if (dmin == 0)  c = -66.f / 25.f;
        else                 c = (float)(12 - dmin) * 0.04f;
        ob[k] = f2bf(zT + u[k] + coef * c);
    }

    uint4 o0, o1;
    o0.x = (u32)ob[0]  | ((u32)ob[1]  << 16);
    o0.y = (u32)ob[2]  | ((u32)ob[3]  << 16);
    o0.z = (u32)ob[4]  | ((u32)ob[5]  << 16);
    o0.w = (u32)ob[6]  | ((u32)ob[7]  << 16);
    o1.x = (u32)ob[8]  | ((u32)ob[9]  << 16);
    o1.y = (u32)ob[10] | ((u32)ob[11] << 16);
    o1.z = (u32)ob[12] | ((u32)ob[13] << 16);
    o1.w = (u32)ob[14] | ((u32)ob[15] << 16);
    uint4* op = (uint4*)(grow + ((size_t)tid << 4));
    op[0] = o0; op[1] = o1;
}

// ---------------------------------------------------------------------------
// Kernel G: fused GEMM, BM=128 BN=96 BK=64, 512 thr = 8 waves (2m x 2n x 2kp),
// 64 iters, one barrier/iter. A LDS 3-deep (waves 0-3 stage, vmcnt(4) lead-2),
// B LDS 2-deep (waves 4-7 stage, vmcnt(0) lead-1, L2-hot). Proven XOR swizzle
// (128B rows, pre-swizzled global source). k-parity reduce via LDS + fused
// bias/std epilogue. 72KB LDS -> 2 blocks/CU = 4 waves/SIMD.
// ---------------------------------------------------------------------------
typedef __attribute__((address_space(1))) void gvoid;
typedef __attribute__((address_space(3))) void lvoid;
#define GLD16(g, l_) __builtin_amdgcn_global_load_lds((gvoid*)(g), (lvoid*)(l_), 16, 0, 0)
#define MF(a, b, c) __builtin_amdgcn_mfma_f32_16x16x32_bf16(a, b, c, 0, 0, 0)

#define ABUF 16384
#define BBASE 49152
#define BBUF 12288

#define STAGE_A2(T, DB) do { \
    char* d_ = Sm + (DB) * ABUF; \
    const size_t go_ = (size_t)((T) + 2) * 128; \
    GLD16(s0 + go_, d_ + dof0); GLD16(s1 + go_, d_ + dof1); \
    GLD16(s2 + go_, d_ + dof2); GLD16(s3 + go_, d_ + dof3); \
} while (0)

#define STAGE_B1(T, DB) do { \
    char* d_ = Sm + BBASE + (DB) * BBUF; \
    const size_t go_ = (size_t)((T) + 1) * 128; \
    GLD16(s0 + go_, d_ + dof0); GLD16(s1 + go_, d_ + dof1); GLD16(s2 + go_, d_ + dof2); \
} while (0)

#define ITER(T, RA, RB, SAB, SBB, VA, VB, SA, SB) do { \
    if (isA) { asm volatile("s_waitcnt vmcnt(" #VA ")" ::: "memory"); } \
    else     { asm volatile("s_waitcnt vmcnt(" #VB ")" ::: "memory"); } \
    __builtin_amdgcn_s_barrier(); \
    __builtin_amdgcn_sched_barrier(0); \
    if (isA) { if (SA) STAGE_A2(T, SAB); } \
    else     { if (SB) STAGE_B1(T, SBB); } \
    __builtin_amdgcn_sched_barrier(0); \
    const char* ab_ = Sm + (RA) * ABUF + aro; \
    const char* bb_ = Sm + BBASE + (RB) * BBUF + bro; \
    bf16x8 a0_ = *(const bf16x8*)(ab_); \
    bf16x8 a1_ = *(const bf16x8*)(ab_ + 2048); \
    bf16x8 a2_ = *(const bf16x8*)(ab_ + 4096); \
    bf16x8 a3_ = *(const bf16x8*)(ab_ + 6144); \
    bf16x8 b0_ = *(const bf16x8*)(bb_); \
    bf16x8 b1_ = *(const bf16x8*)(bb_ + 2048); \
    bf16x8 b2_ = *(const bf16x8*)(bb_ + 4096); \
    asm volatile("s_waitcnt lgkmcnt(0)" ::: "memory"); \
    __builtin_amdgcn_sched_barrier(0); \
    __builtin_amdgcn_s_setprio(1); \
    acc[0][0]=MF(a0_,b0_,acc[0][0]); acc[0][1]=MF(a0_,b1_,acc[0][1]); acc[0][2]=MF(a0_,b2_,acc[0][2]); \
    acc[1][0]=MF(a1_,b0_,acc[1][0]); acc[1][1]=MF(a1_,b1_,acc[1][1]); acc[1][2]=MF(a1_,b2_,acc[1][2]); \
    acc[2][0]=MF(a2_,b0_,acc[2][0]); acc[2][1]=MF(a2_,b1_,acc[2][1]); acc[2][2]=MF(a2_,b2_,acc[2][2]); \
    acc[3][0]=MF(a3_,b0_,acc[3][0]); acc[3][1]=MF(a3_,b1_,acc[3][1]); acc[3][2]=MF(a3_,b2_,acc[3][2]); \
    __builtin_amdgcn_s_setprio(0); \
} while (0)

__global__ __launch_bounds__(512, 4) void gemm_fused(const u16* __restrict__ Abf,
                                                     const u16* __restrict__ Gbf,
                                                     const float* __restrict__ bt,
                                                     const float* __restrict__ bl,
                                                     const float* __restrict__ bh,
                                                     const float* __restrict__ stdv,
                                                     float* __restrict__ out) {
    __shared__ __align__(16) char Sm[73728];   // A 3x16KB | B 2x12KB
    const int tid = threadIdx.x;
    const int l = tid & 63, wid = tid >> 6;          // wid 0..7
    const int kp = wid & 1, wm = (wid >> 1) & 1, wn = wid >> 2;
    const bool isA = (wid < 4);

    // XCD-chunked swizzle: 512 = 8 XCDs x 64; n fastest within chunk
    const int orig = blockIdx.x;
    const int chunk = orig & 7, pos = orig >> 3;
    const int bx = pos & 7;
    const int by = (chunk << 3) + (pos >> 3);
    const int m0 = by * 128;
    const int n0 = bx * 96;

    // ---- staging descriptors: each gld16 covers 8 rows x 128B, pre-swizzled
    // source slot = (l&7) ^ (l>>3)  ==>  LDS(row, s) = M(row, s ^ (row&7))
    const int sgb = (((l & 7) ^ (l >> 3)) << 4);
    const char* s0; const char* s1; const char* s2; const char* s3;
    int dof0, dof1, dof2, dof3;
    if (isA) {
        const int r0 = wid * 32;                      // A rows [r0, r0+32)
        s0 = (const char*)Abf + ((size_t)(m0 + r0 +  0 + (l >> 3)) << 13) + sgb;
        s1 = (const char*)Abf + ((size_t)(m0 + r0 +  8 + (l >> 3)) << 13) + sgb;
        s2 = (const char*)Abf + ((size_t)(m0 + r0 + 16 + (l >> 3)) << 13) + sgb;
        s3 = (const char*)Abf + ((size_t)(m0 + r0 + 24 + (l >> 3)) << 13) + sgb;
        dof0 = r0 * 128; dof1 = dof0 + 1024; dof2 = dof0 + 2048; dof3 = dof0 + 3072;
    } else {
        const int r0 = (wid - 4) * 24;                // B rows [r0, r0+24)
        s0 = (const char*)Gbf + ((size_t)(n0 + r0 +  0 + (l >> 3)) << 13) + sgb;
        s1 = (const char*)Gbf + ((size_t)(n0 + r0 +  8 + (l >> 3)) << 13) + sgb;
        s2 = (const char*)Gbf + ((size_t)(n0 + r0 + 16 + (l >> 3)) << 13) + sgb;
        s3 = s0;
        dof0 = r0 * 128; dof1 = dof0 + 1024; dof2 = dof0 + 2048; dof3 = dof0;
    }

    // ---- fragment read offsets: k-slice [kp*32, +32) of the 64-wide slab ----
    const int slot = ((kp << 2) + (l >> 4)) ^ (l & 7);
    const int aro = (wm * 64 + (l & 15)) * 128 + (slot << 4);
    const int bro = (wn * 48 + (l & 15)) * 128 + (slot << 4);

    f32x4 acc[4][3] = {};

    // ---- prologue: A tiles 0,1 staged; B tile 0 staged ----
    if (isA) {
        GLD16(s0, Sm + dof0); GLD16(s1, Sm + dof1);
        GLD16(s2, Sm + dof2); GLD16(s3, Sm + dof3);
        GLD16(s0 + 128, Sm + ABUF + dof0); GLD16(s1 + 128, Sm + ABUF + dof1);
        GLD16(s2 + 128, Sm + ABUF + dof2); GLD16(s3 + 128, Sm + ABUF + dof3);
    } else {
        GLD16(s0, Sm + BBASE + dof0); GLD16(s1, Sm + BBASE + dof1);
        GLD16(s2, Sm + BBASE + dof2);
    }

    for (int t = 0; t < 60; t += 6) {
        ITER(t + 0, 0, 0, 2, 1, 4, 0, 1, 1);
        ITER(t + 1, 1, 1, 0, 0, 4, 0, 1, 1);
        ITER(t + 2, 2, 0, 1, 1, 4, 0, 1, 1);
        ITER(t + 3, 0, 1, 2, 0, 4, 0, 1, 1);
        ITER(t + 4, 1, 0, 0, 1, 4, 0, 1, 1);
        ITER(t + 5, 2, 1, 1, 0, 4, 0, 1, 1);
    }
    ITER(60, 0, 0, 2, 1, 4, 0, 1, 1);
    ITER(61, 1, 1, 0, 0, 4, 0, 1, 1);
    ITER(62, 2, 0, 1, 1, 4, 0, 0, 1);
    ITER(63, 0, 1, 2, 0, 0, 0, 0, 0);

    // ---- cross-parity reduce (kp1 -> LDS, kp0 adds) + fused bias epilogue ----
    __syncthreads();
    float* red = (float*)Sm;
    const int pb_ = (wm * 2 + wn) * 3264;   // floats; col stride 68 floats (272B)
    const int rr_ = (l >> 4) << 2;
    const int cc_ = l & 15;
    if (kp == 1) {
        #pragma unroll
        for (int m = 0; m < 4; ++m)
            #pragma unroll
            for (int n = 0; n < 3; ++n)
                *(f32x4*)(red + pb_ + (n * 16 + cc_) * 68 + m * 16 + rr_) = acc[m][n];
    }
    __syncthreads();
    if (kp == 0) {
        const int crow = m0 + wm * 64 + rr_;
        const int ccol = n0 + wn * 48 + cc_;
        float btv[3], bsv[3];
        #pragma unroll
        for (int n = 0; n < 3; ++n) {
            const int col = ccol + n * 16;
            if (col < PCOL) { btv[n] = bt[col]; bsv[n] = bl[col] + bh[col]; }
            else            { btv[n] = 0.f; bsv[n] = 0.f; }
        }
        #pragma unroll
        for (int m = 0; m < 4; ++m) {
            const int row = crow + m * 16;
            const float4 sv = *(const float4*)(stdv + row);
            #pragma unroll
            for (int n = 0; n < 3; ++n) {
                const int col = ccol + n * 16;
                if (col < PCOL) {
                    const f32x4 pv = *(const f32x4*)(red + pb_ + (n * 16 + cc_) * 68 + m * 16 + rr_);
                    float* orow = out + (size_t)row * PCOL + col;
                    #pragma unroll
                    for (int j = 0; j < 4; ++j) {
                        const float s = (j == 0) ? sv.x : (j == 1) ? sv.y : (j == 2) ? sv.z : sv.w;
                        orow[(size_t)j * PCOL] = acc[m][n][j] + pv[j] + btv[n] + s * bsv[n];
                    }
                }
            }
        }
    }
}

// ---------------------------------------------------------------------------
extern "C" void kernel_launch(void* const* d_in, const int* in_sizes, int n_in,
                              void* d_out, int out_size, void* d_ws, size_t ws_size,
                              hipStream_t stream) {
    (void)in_sizes; (void)n_in; (void)out_size;
    if (ws_size < WS_MIN) return;

    const float* x  = (const float*)d_in[0];
    const float* Wt = (const float*)d_in[1];
    const float* bt = (const float*)d_in[2];
    const float* Wl = (const float*)d_in[3];
    const float* bl = (const float*)d_in[4];
    const float* Wh = (const float*)d_in[5];
    const float* bh = (const float*)d_in[6];
    float* out = (float*)d_out;

    char* ws = (char*)d_ws;
    u16*   xbf = (u16*)ws;
    u16*   Gm  = (u16*)(ws + WS_XBF_BYTES);
    float* sd  = (float*)(ws + WS_XBF_BYTES + WS_G_BYTES);

    prep_rows<<<NB, 256, 0, stream>>>(x, xbf, sd);
    prep_weights<<<NPAD, 256, 0, stream>>>(Wt, Wl, Wh, Gm);
    gemm_fused<<<512, 512, 0, stream>>>(xbf, Gm, bt, bl, bh, sd, out);
}